// Round 11
// baseline (1145.781 us; speedup 1.0000x reference)
//
#include <hip/hip_runtime.h>
#include <hip/hip_bf16.h>

#define N_   8
#define P_   2048
#define K_   16

typedef const float* fpp;

__device__ __forceinline__ float bcast(float v, int lane){
    return __uint_as_float(__builtin_amdgcn_readlane(__float_as_uint(v), (unsigned)lane));
}

// ---------------- KNN: fp32 distances (ref formula/order), stable top-17, drop self ----------------
__global__ __launch_bounds__(64) void knn_kernel(fpp points, int* idxo){
    __shared__ float sx[P_], sy[P_], sz[P_], sr[P_];
    const int n  = blockIdx.x >> 5;
    const int pl = ((blockIdx.x & 31) << 6) + threadIdx.x;
    const int base = n << 11;
    for (int i = threadIdx.x; i < P_; i += 64){
        float x = points[(base+i)*3+0];
        float y = points[(base+i)*3+1];
        float z = points[(base+i)*3+2];
        sx[i]=x; sy[i]=y; sz[i]=z;
        sr[i] = x*x + y*y + z*z;
    }
    __syncthreads();
    const float px = sx[pl], py = sy[pl], pz = sz[pl], rp = sr[pl];
    float ad[17]; int aq[17];
    #pragma unroll
    for (int j=0;j<17;j++){ ad[j] = __builtin_inff(); aq[j] = 0; }
    for (int q = 0; q < P_; ++q){
        float d = (rp - 2.0f*(px*sx[q] + py*sy[q] + pz*sz[q])) + sr[q];
        if (d < ad[16]){
            #pragma unroll
            for (int j = 16; j >= 1; --j){
                bool  mv = ad[j-1] > d;
                float cd = ad[j]; int cq = aq[j];
                ad[j] = mv ? ad[j-1] : ((cd > d) ? d : cd);
                aq[j] = mv ? aq[j-1] : ((cd > d) ? q : cq);
            }
            if (ad[0] > d){ ad[0] = d; aq[0] = q; }
        }
    }
    const int orow = (base + pl) * K_;
    #pragma unroll
    for (int k=0;k<K_;k++) idxo[orow + k] = base + aq[k+1];
}

// ------ per-point transforms: U,V (conv0 split), AU,AV (attn1 split). 3 waves. ------
__global__ __launch_bounds__(192) void feat_gemm_kernel(fpp feat, fpp w0, fpp aw1,
        float* U, float* V, float* AU, float* AV){
    const int t = threadIdx.x;
    const int w = t >> 6, lane = t & 63;
    const int row0 = blockIdx.x * 16;
    float wreg[64];
    if (w == 0){
        #pragma unroll
        for (int c=0;c<64;c++) wreg[c] = w0[lane*128+c] - w0[lane*128+64+c];
    } else if (w == 1){
        #pragma unroll
        for (int c=0;c<64;c++) wreg[c] = w0[lane*128+64+c];
    } else {
        if (lane < 32){
            #pragma unroll
            for (int c=0;c<64;c++) wreg[c] = aw1[lane*128+c] - aw1[lane*128+64+c];
        } else {
            const int o = lane - 32;
            #pragma unroll
            for (int c=0;c<64;c++) wreg[c] = aw1[o*128+64+c];
        }
    }
    for (int r=0;r<16;r++){
        const int row = row0 + r;
        const float fv = feat[row*64 + lane];
        float acc = 0.f;
        #pragma unroll
        for (int c=0;c<64;c++) acc = fmaf(bcast(fv, c), wreg[c], acc);
        if      (w==0) U[row*64+lane]=acc;
        else if (w==1) V[row*64+lane]=acc;
        else { if (lane<32) AU[row*32+lane]=acc; else AV[row*32+lane-32]=acc; }
    }
}

// ------ dedicated SC stats ------
__global__ __launch_bounds__(128) void sc_stats_kernel(fpp feat, fpp scw, float* scs, float* scq){
    __shared__ float swc[128*65];
    __shared__ float sf[16*64];
    const int t = threadIdx.x;
    for (int i=t;i<8192;i+=128) swc[(i>>6)*65+(i&63)] = scw[i];
    const int row0 = blockIdx.x*16;
    for (int i=t;i<1024;i+=128) sf[i] = feat[row0*64+i];
    __syncthreads();
    float psum=0.f, psq=0.f;
    for (int r=0;r<16;r++){
        float acc = 0.f;
        #pragma unroll
        for (int k=0;k<64;k++) acc = fmaf(sf[r*64+k], swc[t*65+k], acc);
        psum += acc; psq += acc*acc;
    }
    atomicAdd(&scs[t], psum);
    atomicAdd(&scq[t], psq);
}

// ------ attention logits + softmax over K, and BN0 stats of y0 = U[p]+V[q] ------
__global__ __launch_bounds__(256) void attn_bn0_kernel(const int* idx, const float* U, const float* V,
        const float* AU, const float* AV, fpp b1, fpp w2, fpp b2, fpp tau,
        float* attw, float* bn0s, float* bn0q){
    const int t = threadIdx.x, w = t>>6, lane = t&63;
    const int pt0 = blockIdx.x*32 + w*8;
    const int kk = lane >> 2, h = lane & 3;
    float w2r[32];
    #pragma unroll
    for (int c=0;c<32;c++) w2r[c] = w2[h*32+c];
    const float b2v = b2[h];
    const float tv  = tau[0];
    float ssum=0.f, ssq=0.f;
    for (int j=0;j<8;j++){
        const int pt = pt0 + j;
        const int* ip = idx + pt*K_;
        const float uv = U[pt*64+lane];
        for (int k=0;k<K_;k++){
            const int q = ip[k];
            const float v = uv + V[q*64+lane];
            ssum += v; ssq += v*v;
        }
        const int q = ip[kk];
        float a2 = b2v;
        for (int c=0;c<32;c++){
            float a1 = AU[pt*32+c] + AV[q*32+c] + b1[c];
            a1 = a1 > 0.f ? a1 : 0.2f*a1;
            a2 = fmaf(a1, w2r[c], a2);
        }
        const float lt = a2 / tv;
        float m = lt;
        m = fmaxf(m, __shfl_xor(m, 4));  m = fmaxf(m, __shfl_xor(m, 8));
        m = fmaxf(m, __shfl_xor(m, 16)); m = fmaxf(m, __shfl_xor(m, 32));
        const float e = expf(lt - m);
        float s = e;
        s += __shfl_xor(s, 4);  s += __shfl_xor(s, 8);
        s += __shfl_xor(s, 16); s += __shfl_xor(s, 32);
        attw[pt*64 + lane] = e / s;
    }
    __shared__ float rs[256], rq[256];
    rs[t]=ssum; rq[t]=ssq; __syncthreads();
    if (t < 64){
        atomicAdd(&bn0s[t], rs[t]+rs[t+64]+rs[t+128]+rs[t+192]);
        atomicAdd(&bn0q[t], rq[t]+rq[t+64]+rq[t+128]+rq[t+192]);
    }
}

// ------ fold BN into per-channel scale/shift ------
__global__ __launch_bounds__(128) void bn_finalize_kernel(const float* s, const float* q, fpp g, fpp b,
        float inv_cnt, int C, float* scale, float* shift){
    const int c = threadIdx.x;
    if (c < C){
        const float mu  = s[c]*inv_cnt;
        const float var = fmaxf(q[c]*inv_cnt - mu*mu, 0.f);
        const float sc  = g[c] * rsqrtf(var + 1e-5f);
        scale[c]=sc; shift[c] = b[c] - mu*sc;
    }
}

// ------ conv1 stats ------
__global__ __launch_bounds__(256) void conv1_stats_kernel(const int* idx, const float* U, const float* V,
        fpp w1, const float* sc0, const float* sh0, float* bn1s, float* bn1q){
    const int t=threadIdx.x, w=t>>6, lane=t&63;
    float wreg[64];
    #pragma unroll
    for (int c=0;c<64;c++) wreg[c] = w1[lane*64+c];
    const float s0 = sc0[lane], h0 = sh0[lane];
    const int sbase = blockIdx.x*128 + w*32;
    float ssum=0.f, ssq=0.f;
    for (int i=0;i<32;i++){
        const int s = sbase + i;
        const int p = s >> 4;
        const int q = idx[s];
        const float a = fmaxf(fmaf(U[p*64+lane] + V[q*64+lane], s0, h0), 0.f);
        float acc = 0.f;
        #pragma unroll
        for (int c=0;c<64;c++) acc = fmaf(bcast(a, c), wreg[c], acc);
        ssum += acc; ssq += acc*acc;
    }
    __shared__ float rs[256], rq[256];
    rs[t]=ssum; rq[t]=ssq; __syncthreads();
    if (t<64){
        atomicAdd(&bn1s[t], rs[t]+rs[t+64]+rs[t+128]+rs[t+192]);
        atomicAdd(&bn1q[t], rq[t]+rq[t+64]+rq[t+128]+rq[t+192]);
    }
}

// ------ conv2 stats ------
__global__ __launch_bounds__(256) void conv2_stats_kernel(const int* idx, const float* U, const float* V,
        fpp w1, fpp w2c, const float* sc0, const float* sh0, const float* sc1, const float* sh1,
        float* bn2s, float* bn2q){
    __shared__ float sw2[128*65];
    __shared__ float rs[512], rq[512];
    const int t=threadIdx.x, w=t>>6, lane=t&63;
    for (int i=t;i<8192;i+=256) sw2[(i>>6)*65+(i&63)] = w2c[i];
    float w1r[64];
    #pragma unroll
    for (int c=0;c<64;c++) w1r[c] = w1[lane*64+c];
    __syncthreads();
    const float s0=sc0[lane], h0=sh0[lane], s1=sc1[lane], h1=sh1[lane];
    const int sbase = blockIdx.x*128 + w*32;
    float s0a=0.f,q0a=0.f,s1a=0.f,q1a=0.f;
    for (int i=0;i<32;i++){
        const int s = sbase + i;
        const int p = s >> 4;
        const int q = idx[s];
        const float a0 = fmaxf(fmaf(U[p*64+lane] + V[q*64+lane], s0, h0), 0.f);
        float y1 = 0.f;
        #pragma unroll
        for (int c=0;c<64;c++) y1 = fmaf(bcast(a0, c), w1r[c], y1);
        const float a1 = fmaxf(fmaf(y1, s1, h1), 0.f);
        float acc0=0.f, acc1=0.f;
        #pragma unroll
        for (int c=0;c<64;c++){
            const float bc = bcast(a1, c);
            acc0 = fmaf(bc, sw2[lane*65+c],      acc0);
            acc1 = fmaf(bc, sw2[(lane+64)*65+c], acc1);
        }
        s0a+=acc0; q0a+=acc0*acc0; s1a+=acc1; q1a+=acc1*acc1;
    }
    rs[t]=s0a; rs[256+t]=s1a; rq[t]=q0a; rq[256+t]=q1a; __syncthreads();
    if (t<64){
        atomicAdd(&bn2s[t],    rs[t]+rs[t+64]+rs[t+128]+rs[t+192]);
        atomicAdd(&bn2q[t],    rq[t]+rq[t+64]+rq[t+128]+rq[t+192]);
        atomicAdd(&bn2s[64+t], rs[256+t]+rs[256+t+64]+rs[256+t+128]+rs[256+t+192]);
        atomicAdd(&bn2q[64+t], rq[256+t]+rq[256+t+64]+rq[256+t+128]+rq[256+t+192]);
    }
}

// ------ combine ------
__global__ __launch_bounds__(256) void combine_kernel(const int* idx, const float* U, const float* V,
        fpp w1, fpp w2c, const float* sc0, const float* sh0, const float* sc1, const float* sh1,
        const float* sc2, const float* sh2, const float* attw, float* xcomb, float* msum){
    __shared__ float sw2[128*65];
    __shared__ float rs[512];
    const int t=threadIdx.x, w=t>>6, lane=t&63;
    for (int i=t;i<8192;i+=256) sw2[(i>>6)*65+(i&63)] = w2c[i];
    float w1r[64];
    #pragma unroll
    for (int c=0;c<64;c++) w1r[c] = w1[lane*64+c];
    __syncthreads();
    const float s0=sc0[lane], h0=sh0[lane], s1=sc1[lane], h1=sh1[lane];
    const float s2a=sc2[lane], h2a=sh2[lane], s2b=sc2[64+lane], h2b=sh2[64+lane];
    const int pt0 = blockIdx.x*16 + w*4;
    const int hsel = lane >> 5;
    float m0=0.f, m1=0.f;
    for (int j=0;j<4;j++){
        const int pt = pt0 + j;
        const float uval = U[pt*64+lane];
        float acc0=0.f, acc1=0.f;
        for (int k=0;k<K_;k++){
            const int s = pt*K_ + k;
            const int q = idx[s];
            const float a0 = fmaxf(fmaf(uval + V[q*64+lane], s0, h0), 0.f);
            float y1 = 0.f;
            #pragma unroll
            for (int c=0;c<64;c++) y1 = fmaf(bcast(a0, c), w1r[c], y1);
            const float a1 = fmaxf(fmaf(y1, s1, h1), 0.f);
            float y20=0.f, y21=0.f;
            #pragma unroll
            for (int c=0;c<64;c++){
                const float bc = bcast(a1, c);
                y20 = fmaf(bc, sw2[lane*65+c],      y20);
                y21 = fmaf(bc, sw2[(lane+64)*65+c], y21);
            }
            const float r0 = fmaxf(fmaf(y20, s2a, h2a), 0.f);
            const float r1 = fmaxf(fmaf(y21, s2b, h2b), 0.f);
            acc0 = fmaf(r0, attw[s*4 + hsel],     acc0);
            acc1 = fmaf(r1, attw[s*4 + 2 + hsel], acc1);
        }
        xcomb[pt*128+lane]    = acc0;
        xcomb[pt*128+64+lane] = acc1;
        m0 += acc0; m1 += acc1;
    }
    rs[t]=m0; rs[256+t]=m1; __syncthreads();
    if (t<64){
        const int n = (blockIdx.x*16) >> 11;
        atomicAdd(&msum[n*128+t],    rs[t]+rs[t+64]+rs[t+128]+rs[t+192]);
        atomicAdd(&msum[n*128+64+t], rs[256+t]+rs[256+t+64]+rs[256+t+128]+rs[256+t+192]);
    }
}

// ------ SE gate ------
__global__ __launch_bounds__(128) void se_kernel(const float* msum, fpp w1se, fpp w2se, float* sev){
    __shared__ float tl[32];
    const int t = threadIdx.x;
    for (int n=0;n<N_;n++){
        if (t < 32){
            float acc=0.f;
            for (int c=0;c<128;c++) acc = fmaf(msum[n*128+c]*(1.f/2048.f), w1se[t*128+c], acc);
            tl[t] = fmaxf(acc, 0.f);
        }
        __syncthreads();
        float acc=0.f;
        for (int hh=0;hh<32;hh++) acc = fmaf(tl[hh], w2se[t*32+hh], acc);
        sev[n*128+t] = 1.f/(1.f+expf(-acc));
        __syncthreads();
    }
}

// ------ out = xcomb*s + relu(bn_sc(feat @ sc_w^T))  — FP32 OUTPUT ------
__global__ __launch_bounds__(128) void final_kernel(fpp feat, fpp scw, const float* xcomb,
        const float* sev, const float* scsc, const float* shsc, float* out){
    __shared__ float swc[128*65];
    __shared__ float sf[16*64];
    const int t = threadIdx.x;
    for (int i=t;i<8192;i+=128) swc[(i>>6)*65+(i&63)] = scw[i];
    const int row0 = blockIdx.x*16;
    for (int i=t;i<1024;i+=128) sf[i] = feat[row0*64+i];
    __syncthreads();
    const int c = t;
    const float scl = scsc[c], shf = shsc[c];
    for (int r=0;r<16;r++){
        const int row = row0 + r;
        float acc = 0.f;
        #pragma unroll
        for (int k=0;k<64;k++) acc = fmaf(sf[r*64+k], swc[c*65+k], acc);
        const int n = row >> 11;
        out[row*128+c] = xcomb[row*128+c]*sev[n*128+c] + fmaxf(fmaf(acc, scl, shf), 0.f);
    }
}

extern "C" void kernel_launch(void* const* d_in, const int* in_sizes, int n_in,
                              void* d_out, int out_size, void* d_ws, size_t ws_size,
                              hipStream_t stream) {
    fpp points  = (fpp)d_in[0];
    fpp feat    = (fpp)d_in[1];
    fpp conv_w0 = (fpp)d_in[2];
    fpp conv_w1 = (fpp)d_in[3];
    fpp conv_w2 = (fpp)d_in[4];
    fpp bn_g0 = (fpp)d_in[5],  bn_b0 = (fpp)d_in[6];
    fpp bn_g1 = (fpp)d_in[7],  bn_b1 = (fpp)d_in[8];
    fpp bn_g2 = (fpp)d_in[9],  bn_b2 = (fpp)d_in[10];
    fpp attn_w1 = (fpp)d_in[11], attn_b1 = (fpp)d_in[12];
    fpp attn_w2 = (fpp)d_in[13], attn_b2 = (fpp)d_in[14];
    fpp tau  = (fpp)d_in[15];
    fpp sc_w = (fpp)d_in[16], sc_g = (fpp)d_in[17], sc_b = (fpp)d_in[18];
    fpp se_w1 = (fpp)d_in[19], se_w2 = (fpp)d_in[20];

    float* W = (float*)d_ws;
    float* BN0S=W+0;    float* BN0Q=W+64;
    float* BN1S=W+128;  float* BN1Q=W+192;
    float* BN2S=W+256;  float* BN2Q=W+384;
    float* SCS =W+512;  float* SCQ =W+640;
    float* SC0 =W+768;  float* SH0 =W+832;
    float* SC1 =W+896;  float* SH1 =W+960;
    float* SC2 =W+1024; float* SH2 =W+1152;
    float* SCSC=W+1280; float* SHSC=W+1408;
    float* MSUM=W+1536; float* SEV =W+2560;
    int*   IDX  = (int*)(W + 4096);
    float* U    = W + 266240;
    float* V    = U + 1048576;
    float* AU   = V + 1048576;
    float* AV   = AU + 524288;
    float* ATTW = AV + 524288;
    float* XCOMB= ATTW + 1048576;              // ends 6,557,696 floats (~26.2 MB)

    hipMemsetAsync(d_ws, 0, 4096*sizeof(float), stream);

    knn_kernel<<<256, 64, 0, stream>>>(points, IDX);
    feat_gemm_kernel<<<1024, 192, 0, stream>>>(feat, conv_w0, attn_w1, U, V, AU, AV);
    sc_stats_kernel<<<1024, 128, 0, stream>>>(feat, sc_w, SCS, SCQ);
    attn_bn0_kernel<<<512, 256, 0, stream>>>(IDX, U, V, AU, AV,
                                             attn_b1, attn_w2, attn_b2, tau,
                                             ATTW, BN0S, BN0Q);
    bn_finalize_kernel<<<1, 128, 0, stream>>>(BN0S, BN0Q, bn_g0, bn_b0,
                                              1.0f/262144.0f, 64, SC0, SH0);
    bn_finalize_kernel<<<1, 128, 0, stream>>>(SCS, SCQ, sc_g, sc_b,
                                              1.0f/16384.0f, 128, SCSC, SHSC);
    conv1_stats_kernel<<<2048, 256, 0, stream>>>(IDX, U, V, conv_w1, SC0, SH0, BN1S, BN1Q);
    bn_finalize_kernel<<<1, 128, 0, stream>>>(BN1S, BN1Q, bn_g1, bn_b1,
                                              1.0f/262144.0f, 64, SC1, SH1);
    conv2_stats_kernel<<<2048, 256, 0, stream>>>(IDX, U, V, conv_w1, conv_w2,
                                                 SC0, SH0, SC1, SH1, BN2S, BN2Q);
    bn_finalize_kernel<<<1, 128, 0, stream>>>(BN2S, BN2Q, bn_g2, bn_b2,
                                              1.0f/262144.0f, 128, SC2, SH2);
    combine_kernel<<<1024, 256, 0, stream>>>(IDX, U, V, conv_w1, conv_w2,
                                             SC0, SH0, SC1, SH1, SC2, SH2,
                                             ATTW, XCOMB, MSUM);
    se_kernel<<<1, 128, 0, stream>>>(MSUM, se_w1, se_w2, SEV);
    final_kernel<<<1024, 128, 0, stream>>>(feat, sc_w, XCOMB, SEV, SCSC, SHSC,
                                           (float*)d_out);
}

// Round 12
// 726.363 us; speedup vs baseline: 1.5774x; 1.5774x over previous
//
#include <hip/hip_runtime.h>
#include <hip/hip_bf16.h>

#define N_   8
#define P_   2048
#define K_   16

typedef const float* fpp;

__device__ __forceinline__ float bcast(float v, int lane){
    return __uint_as_float(__builtin_amdgcn_readlane(__float_as_uint(v), (unsigned)lane));
}

// ---- KNN v2: 8 threads/point, chunked stable top-17, padded float4 LDS ----
// grid 512 x 256. 32 points/block. LDS ~59KB -> 2 blocks/CU -> 8 waves/CU.
__global__ __launch_bounds__(256) void knn_kernel(fpp points, int* idxo){
    __shared__ float4 scand[2056];            // pos(q) = q + (q>>8): kills 8-way bank alias
    __shared__ float  md[32*136];
    __shared__ unsigned short mi[32*136];
    const int t = threadIdx.x;
    const int n  = blockIdx.x >> 6;           // 64 blocks per batch
    const int p0 = (blockIdx.x & 63) * 32;
    const int base = n << 11;
    for (int i = t; i < 2048; i += 256){
        float x = points[(base+i)*3+0];
        float y = points[(base+i)*3+1];
        float z = points[(base+i)*3+2];
        scand[i + (i>>8)] = make_float4(x, y, z, x*x + y*y + z*z);
    }
    __syncthreads();
    const int pp  = t >> 3;                   // local point 0..31
    const int sub = t & 7;                    // chunk 0..7
    const int pl  = p0 + pp;
    const float4 me = scand[pl + (pl>>8)];
    const float px = me.x, py = me.y, pz = me.z, rp = me.w;
    float ad[17]; int aq[17];
    #pragma unroll
    for (int j=0;j<17;j++){ ad[j] = __builtin_inff(); aq[j] = 0; }
    const int qbase = sub << 8;
    for (int i = 0; i < 256; ++i){
        const int q = qbase + i;
        const float4 c = scand[q + sub];      // q>>8 == sub inside chunk
        const float d = (rp - 2.0f*(px*c.x + py*c.y + pz*c.z)) + c.w;
        if (d < ad[16]){
            #pragma unroll
            for (int j = 16; j >= 1; --j){
                bool  mv = ad[j-1] > d;
                float cd = ad[j]; int cq = aq[j];
                ad[j] = mv ? ad[j-1] : ((cd > d) ? d : cd);
                aq[j] = mv ? aq[j-1] : ((cd > d) ? q : cq);
            }
            if (ad[0] > d){ ad[0] = d; aq[0] = q; }
        }
    }
    const int mbase = pp*136 + sub*17;
    #pragma unroll
    for (int j=0;j<17;j++){ md[mbase+j] = ad[j]; mi[mbase+j] = (unsigned short)aq[j]; }
    __syncthreads();
    if (sub == 0){
        float fd[17]; int fq[17];
        #pragma unroll
        for (int j=0;j<17;j++){ fd[j] = __builtin_inff(); fq[j] = 0; }
        const int eb = pp*136;
        for (int e = 0; e < 136; ++e){        // lists ascending per chunk, chunks in index order -> stable
            const float d = md[eb+e];
            const int   q = (int)mi[eb+e];
            if (d < fd[16]){
                #pragma unroll
                for (int j = 16; j >= 1; --j){
                    bool  mv = fd[j-1] > d;
                    float cd = fd[j]; int cq = fq[j];
                    fd[j] = mv ? fd[j-1] : ((cd > d) ? d : cd);
                    fq[j] = mv ? fq[j-1] : ((cd > d) ? q : cq);
                }
                if (fd[0] > d){ fd[0] = d; fq[0] = q; }
            }
        }
        const int orow = (base + pl) * K_;
        #pragma unroll
        for (int k=0;k<K_;k++) idxo[orow + k] = base + fq[k+1];   // drop self
    }
}

// ------ per-point transforms: U,V (conv0 split), AU,AV (attn1 split). 3 waves. ------
__global__ __launch_bounds__(192) void feat_gemm_kernel(fpp feat, fpp w0, fpp aw1,
        float* U, float* V, float* AU, float* AV){
    const int t = threadIdx.x;
    const int w = t >> 6, lane = t & 63;
    const int row0 = blockIdx.x * 16;
    float wreg[64];
    if (w == 0){
        #pragma unroll
        for (int c=0;c<64;c++) wreg[c] = w0[lane*128+c] - w0[lane*128+64+c];
    } else if (w == 1){
        #pragma unroll
        for (int c=0;c<64;c++) wreg[c] = w0[lane*128+64+c];
    } else {
        if (lane < 32){
            #pragma unroll
            for (int c=0;c<64;c++) wreg[c] = aw1[lane*128+c] - aw1[lane*128+64+c];
        } else {
            const int o = lane - 32;
            #pragma unroll
            for (int c=0;c<64;c++) wreg[c] = aw1[o*128+64+c];
        }
    }
    for (int r=0;r<16;r++){
        const int row = row0 + r;
        const float fv = feat[row*64 + lane];
        float acc = 0.f;
        #pragma unroll
        for (int c=0;c<64;c++) acc = fmaf(bcast(fv, c), wreg[c], acc);
        if      (w==0) U[row*64+lane]=acc;
        else if (w==1) V[row*64+lane]=acc;
        else { if (lane<32) AU[row*32+lane]=acc; else AV[row*32+lane-32]=acc; }
    }
}

// ------ dedicated SC stats ------
__global__ __launch_bounds__(128) void sc_stats_kernel(fpp feat, fpp scw, float* scs, float* scq){
    __shared__ float swc[128*65];
    __shared__ float sf[16*64];
    const int t = threadIdx.x;
    for (int i=t;i<8192;i+=128) swc[(i>>6)*65+(i&63)] = scw[i];
    const int row0 = blockIdx.x*16;
    for (int i=t;i<1024;i+=128) sf[i] = feat[row0*64+i];
    __syncthreads();
    float psum=0.f, psq=0.f;
    for (int r=0;r<16;r++){
        float acc = 0.f;
        #pragma unroll
        for (int k=0;k<64;k++) acc = fmaf(sf[r*64+k], swc[t*65+k], acc);
        psum += acc; psq += acc*acc;
    }
    atomicAdd(&scs[t], psum);
    atomicAdd(&scq[t], psq);
}

// ------ attention logits + softmax over K, and BN0 stats of y0 = U[p]+V[q] ------
__global__ __launch_bounds__(256) void attn_bn0_kernel(const int* idx, const float* U, const float* V,
        const float* AU, const float* AV, fpp b1, fpp w2, fpp b2, fpp tau,
        float* attw, float* bn0s, float* bn0q){
    const int t = threadIdx.x, w = t>>6, lane = t&63;
    const int pt0 = blockIdx.x*32 + w*8;
    const int kk = lane >> 2, h = lane & 3;
    float w2r[32];
    #pragma unroll
    for (int c=0;c<32;c++) w2r[c] = w2[h*32+c];
    const float b2v = b2[h];
    const float tv  = tau[0];
    float ssum=0.f, ssq=0.f;
    for (int j=0;j<8;j++){
        const int pt = pt0 + j;
        const int* ip = idx + pt*K_;
        const float uv = U[pt*64+lane];
        for (int k=0;k<K_;k++){
            const int q = ip[k];
            const float v = uv + V[q*64+lane];
            ssum += v; ssq += v*v;
        }
        const int q = ip[kk];
        float a2 = b2v;
        for (int c=0;c<32;c++){
            float a1 = AU[pt*32+c] + AV[q*32+c] + b1[c];
            a1 = a1 > 0.f ? a1 : 0.2f*a1;
            a2 = fmaf(a1, w2r[c], a2);
        }
        const float lt = a2 / tv;
        float m = lt;
        m = fmaxf(m, __shfl_xor(m, 4));  m = fmaxf(m, __shfl_xor(m, 8));
        m = fmaxf(m, __shfl_xor(m, 16)); m = fmaxf(m, __shfl_xor(m, 32));
        const float e = expf(lt - m);
        float s = e;
        s += __shfl_xor(s, 4);  s += __shfl_xor(s, 8);
        s += __shfl_xor(s, 16); s += __shfl_xor(s, 32);
        attw[pt*64 + lane] = e / s;
    }
    __shared__ float rs[256], rq[256];
    rs[t]=ssum; rq[t]=ssq; __syncthreads();
    if (t < 64){
        atomicAdd(&bn0s[t], rs[t]+rs[t+64]+rs[t+128]+rs[t+192]);
        atomicAdd(&bn0q[t], rq[t]+rq[t+64]+rq[t+128]+rq[t+192]);
    }
}

// ------ fold BN into per-channel scale/shift ------
__global__ __launch_bounds__(128) void bn_finalize_kernel(const float* s, const float* q, fpp g, fpp b,
        float inv_cnt, int C, float* scale, float* shift){
    const int c = threadIdx.x;
    if (c < C){
        const float mu  = s[c]*inv_cnt;
        const float var = fmaxf(q[c]*inv_cnt - mu*mu, 0.f);
        const float sc  = g[c] * rsqrtf(var + 1e-5f);
        scale[c]=sc; shift[c] = b[c] - mu*sc;
    }
}

// ------ conv1 stats ------
__global__ __launch_bounds__(256) void conv1_stats_kernel(const int* idx, const float* U, const float* V,
        fpp w1, const float* sc0, const float* sh0, float* bn1s, float* bn1q){
    const int t=threadIdx.x, w=t>>6, lane=t&63;
    float wreg[64];
    #pragma unroll
    for (int c=0;c<64;c++) wreg[c] = w1[lane*64+c];
    const float s0 = sc0[lane], h0 = sh0[lane];
    const int sbase = blockIdx.x*128 + w*32;
    float ssum=0.f, ssq=0.f;
    for (int i=0;i<32;i++){
        const int s = sbase + i;
        const int p = s >> 4;
        const int q = idx[s];
        const float a = fmaxf(fmaf(U[p*64+lane] + V[q*64+lane], s0, h0), 0.f);
        float acc = 0.f;
        #pragma unroll
        for (int c=0;c<64;c++) acc = fmaf(bcast(a, c), wreg[c], acc);
        ssum += acc; ssq += acc*acc;
    }
    __shared__ float rs[256], rq[256];
    rs[t]=ssum; rq[t]=ssq; __syncthreads();
    if (t<64){
        atomicAdd(&bn1s[t], rs[t]+rs[t+64]+rs[t+128]+rs[t+192]);
        atomicAdd(&bn1q[t], rq[t]+rq[t+64]+rq[t+128]+rq[t+192]);
    }
}

// ------ conv2 stats (+ optional Y2 materialization) ------
__global__ __launch_bounds__(256) void conv2_stats_kernel(const int* idx, const float* U, const float* V,
        fpp w1, fpp w2c, const float* sc0, const float* sh0, const float* sc1, const float* sh1,
        float* bn2s, float* bn2q, float* y2out, int storeY2){
    __shared__ float sw2[128*65];
    __shared__ float rs[512], rq[512];
    const int t=threadIdx.x, w=t>>6, lane=t&63;
    for (int i=t;i<8192;i+=256) sw2[(i>>6)*65+(i&63)] = w2c[i];
    float w1r[64];
    #pragma unroll
    for (int c=0;c<64;c++) w1r[c] = w1[lane*64+c];
    __syncthreads();
    const float s0=sc0[lane], h0=sh0[lane], s1=sc1[lane], h1=sh1[lane];
    const int sbase = blockIdx.x*128 + w*32;
    float s0a=0.f,q0a=0.f,s1a=0.f,q1a=0.f;
    for (int i=0;i<32;i++){
        const int s = sbase + i;
        const int p = s >> 4;
        const int q = idx[s];
        const float a0 = fmaxf(fmaf(U[p*64+lane] + V[q*64+lane], s0, h0), 0.f);
        float y1 = 0.f;
        #pragma unroll
        for (int c=0;c<64;c++) y1 = fmaf(bcast(a0, c), w1r[c], y1);
        const float a1 = fmaxf(fmaf(y1, s1, h1), 0.f);
        float acc0=0.f, acc1=0.f;
        #pragma unroll
        for (int c=0;c<64;c++){
            const float bc = bcast(a1, c);
            acc0 = fmaf(bc, sw2[lane*65+c],      acc0);
            acc1 = fmaf(bc, sw2[(lane+64)*65+c], acc1);
        }
        if (storeY2){ y2out[s*128+lane] = acc0; y2out[s*128+64+lane] = acc1; }
        s0a+=acc0; q0a+=acc0*acc0; s1a+=acc1; q1a+=acc1*acc1;
    }
    rs[t]=s0a; rs[256+t]=s1a; rq[t]=q0a; rq[256+t]=q1a; __syncthreads();
    if (t<64){
        atomicAdd(&bn2s[t],    rs[t]+rs[t+64]+rs[t+128]+rs[t+192]);
        atomicAdd(&bn2q[t],    rq[t]+rq[t+64]+rq[t+128]+rq[t+192]);
        atomicAdd(&bn2s[64+t], rs[256+t]+rs[256+t+64]+rs[256+t+128]+rs[256+t+192]);
        atomicAdd(&bn2q[64+t], rq[256+t]+rq[256+t+64]+rq[256+t+128]+rq[256+t+192]);
    }
}

// ------ combine (fast path): read materialized Y2, BW-bound ------
__global__ __launch_bounds__(256) void combine_fast_kernel(const float* y2, const float* attw,
        const float* sc2, const float* sh2, float* xcomb, float* msum){
    __shared__ float rs[512];
    const int t=threadIdx.x, w=t>>6, lane=t&63;
    const float s2a=sc2[lane], h2a=sh2[lane], s2b=sc2[64+lane], h2b=sh2[64+lane];
    const int pt0 = blockIdx.x*16 + w*4;
    const int hsel = lane >> 5;
    float m0=0.f, m1=0.f;
    for (int j=0;j<4;j++){
        const int pt = pt0 + j;
        float acc0=0.f, acc1=0.f;
        for (int k=0;k<K_;k++){
            const int s = pt*K_ + k;
            const float r0 = fmaxf(fmaf(y2[s*128+lane],    s2a, h2a), 0.f);
            const float r1 = fmaxf(fmaf(y2[s*128+64+lane], s2b, h2b), 0.f);
            acc0 = fmaf(r0, attw[s*4 + hsel],     acc0);
            acc1 = fmaf(r1, attw[s*4 + 2 + hsel], acc1);
        }
        xcomb[pt*128+lane]    = acc0;
        xcomb[pt*128+64+lane] = acc1;
        m0 += acc0; m1 += acc1;
    }
    rs[t]=m0; rs[256+t]=m1; __syncthreads();
    if (t<64){
        const int n = (blockIdx.x*16) >> 11;
        atomicAdd(&msum[n*128+t],    rs[t]+rs[t+64]+rs[t+128]+rs[t+192]);
        atomicAdd(&msum[n*128+64+t], rs[256+t]+rs[256+t+64]+rs[256+t+128]+rs[256+t+192]);
    }
}

// ------ combine (fallback: recompute, R11-identical) ------
__global__ __launch_bounds__(256) void combine_kernel(const int* idx, const float* U, const float* V,
        fpp w1, fpp w2c, const float* sc0, const float* sh0, const float* sc1, const float* sh1,
        const float* sc2, const float* sh2, const float* attw, float* xcomb, float* msum){
    __shared__ float sw2[128*65];
    __shared__ float rs[512];
    const int t=threadIdx.x, w=t>>6, lane=t&63;
    for (int i=t;i<8192;i+=256) sw2[(i>>6)*65+(i&63)] = w2c[i];
    float w1r[64];
    #pragma unroll
    for (int c=0;c<64;c++) w1r[c] = w1[lane*64+c];
    __syncthreads();
    const float s0=sc0[lane], h0=sh0[lane], s1=sc1[lane], h1=sh1[lane];
    const float s2a=sc2[lane], h2a=sh2[lane], s2b=sc2[64+lane], h2b=sh2[64+lane];
    const int pt0 = blockIdx.x*16 + w*4;
    const int hsel = lane >> 5;
    float m0=0.f, m1=0.f;
    for (int j=0;j<4;j++){
        const int pt = pt0 + j;
        const float uval = U[pt*64+lane];
        float acc0=0.f, acc1=0.f;
        for (int k=0;k<K_;k++){
            const int s = pt*K_ + k;
            const int q = idx[s];
            const float a0 = fmaxf(fmaf(uval + V[q*64+lane], s0, h0), 0.f);
            float y1 = 0.f;
            #pragma unroll
            for (int c=0;c<64;c++) y1 = fmaf(bcast(a0, c), w1r[c], y1);
            const float a1 = fmaxf(fmaf(y1, s1, h1), 0.f);
            float y20=0.f, y21=0.f;
            #pragma unroll
            for (int c=0;c<64;c++){
                const float bc = bcast(a1, c);
                y20 = fmaf(bc, sw2[lane*65+c],      y20);
                y21 = fmaf(bc, sw2[(lane+64)*65+c], y21);
            }
            const float r0 = fmaxf(fmaf(y20, s2a, h2a), 0.f);
            const float r1 = fmaxf(fmaf(y21, s2b, h2b), 0.f);
            acc0 = fmaf(r0, attw[s*4 + hsel],     acc0);
            acc1 = fmaf(r1, attw[s*4 + 2 + hsel], acc1);
        }
        xcomb[pt*128+lane]    = acc0;
        xcomb[pt*128+64+lane] = acc1;
        m0 += acc0; m1 += acc1;
    }
    rs[t]=m0; rs[256+t]=m1; __syncthreads();
    if (t<64){
        const int n = (blockIdx.x*16) >> 11;
        atomicAdd(&msum[n*128+t],    rs[t]+rs[t+64]+rs[t+128]+rs[t+192]);
        atomicAdd(&msum[n*128+64+t], rs[256+t]+rs[256+t+64]+rs[256+t+128]+rs[256+t+192]);
    }
}

// ------ SE gate ------
__global__ __launch_bounds__(128) void se_kernel(const float* msum, fpp w1se, fpp w2se, float* sev){
    __shared__ float tl[32];
    const int t = threadIdx.x;
    for (int n=0;n<N_;n++){
        if (t < 32){
            float acc=0.f;
            for (int c=0;c<128;c++) acc = fmaf(msum[n*128+c]*(1.f/2048.f), w1se[t*128+c], acc);
            tl[t] = fmaxf(acc, 0.f);
        }
        __syncthreads();
        float acc=0.f;
        for (int hh=0;hh<32;hh++) acc = fmaf(tl[hh], w2se[t*32+hh], acc);
        sev[n*128+t] = 1.f/(1.f+expf(-acc));
        __syncthreads();
    }
}

// ------ out = xcomb*s + relu(bn_sc(feat @ sc_w^T)) — fp32 out ------
__global__ __launch_bounds__(128) void final_kernel(fpp feat, fpp scw, const float* xcomb,
        const float* sev, const float* scsc, const float* shsc, float* out){
    __shared__ float swc[128*65];
    __shared__ float sf[16*64];
    const int t = threadIdx.x;
    for (int i=t;i<8192;i+=128) swc[(i>>6)*65+(i&63)] = scw[i];
    const int row0 = blockIdx.x*16;
    for (int i=t;i<1024;i+=128) sf[i] = feat[row0*64+i];
    __syncthreads();
    const int c = t;
    const float scl = scsc[c], shf = shsc[c];
    for (int r=0;r<16;r++){
        const int row = row0 + r;
        float acc = 0.f;
        #pragma unroll
        for (int k=0;k<64;k++) acc = fmaf(sf[r*64+k], swc[c*65+k], acc);
        const int n = row >> 11;
        out[row*128+c] = xcomb[row*128+c]*sev[n*128+c] + fmaxf(fmaf(acc, scl, shf), 0.f);
    }
}

extern "C" void kernel_launch(void* const* d_in, const int* in_sizes, int n_in,
                              void* d_out, int out_size, void* d_ws, size_t ws_size,
                              hipStream_t stream) {
    fpp points  = (fpp)d_in[0];
    fpp feat    = (fpp)d_in[1];
    fpp conv_w0 = (fpp)d_in[2];
    fpp conv_w1 = (fpp)d_in[3];
    fpp conv_w2 = (fpp)d_in[4];
    fpp bn_g0 = (fpp)d_in[5],  bn_b0 = (fpp)d_in[6];
    fpp bn_g1 = (fpp)d_in[7],  bn_b1 = (fpp)d_in[8];
    fpp bn_g2 = (fpp)d_in[9],  bn_b2 = (fpp)d_in[10];
    fpp attn_w1 = (fpp)d_in[11], attn_b1 = (fpp)d_in[12];
    fpp attn_w2 = (fpp)d_in[13], attn_b2 = (fpp)d_in[14];
    fpp tau  = (fpp)d_in[15];
    fpp sc_w = (fpp)d_in[16], sc_g = (fpp)d_in[17], sc_b = (fpp)d_in[18];
    fpp se_w1 = (fpp)d_in[19], se_w2 = (fpp)d_in[20];

    float* W = (float*)d_ws;
    float* BN0S=W+0;    float* BN0Q=W+64;
    float* BN1S=W+128;  float* BN1Q=W+192;
    float* BN2S=W+256;  float* BN2Q=W+384;
    float* SCS =W+512;  float* SCQ =W+640;
    float* SC0 =W+768;  float* SH0 =W+832;
    float* SC1 =W+896;  float* SH1 =W+960;
    float* SC2 =W+1024; float* SH2 =W+1152;
    float* SCSC=W+1280; float* SHSC=W+1408;
    float* MSUM=W+1536; float* SEV =W+2560;
    int*   IDX  = (int*)(W + 4096);
    float* U    = W + 266240;
    float* V    = U + 1048576;
    float* AU   = V + 1048576;
    float* AV   = AU + 524288;
    float* ATTW = AV + 524288;
    float* XCOMB= ATTW + 1048576;              // ends 6,557,696 floats
    float* Y2   = W + 6557696;                 // 33,554,432 floats (134 MB)
    const size_t NEED = (6557696ULL + 33554432ULL) * 4ULL;   // ~160.5 MB
    const int useY2 = (ws_size >= NEED) ? 1 : 0;

    hipMemsetAsync(d_ws, 0, 4096*sizeof(float), stream);

    knn_kernel<<<512, 256, 0, stream>>>(points, IDX);
    feat_gemm_kernel<<<1024, 192, 0, stream>>>(feat, conv_w0, attn_w1, U, V, AU, AV);
    sc_stats_kernel<<<1024, 128, 0, stream>>>(feat, sc_w, SCS, SCQ);
    attn_bn0_kernel<<<512, 256, 0, stream>>>(IDX, U, V, AU, AV,
                                             attn_b1, attn_w2, attn_b2, tau,
                                             ATTW, BN0S, BN0Q);
    bn_finalize_kernel<<<1, 128, 0, stream>>>(BN0S, BN0Q, bn_g0, bn_b0,
                                              1.0f/262144.0f, 64, SC0, SH0);
    bn_finalize_kernel<<<1, 128, 0, stream>>>(SCS, SCQ, sc_g, sc_b,
                                              1.0f/16384.0f, 128, SCSC, SHSC);
    conv1_stats_kernel<<<2048, 256, 0, stream>>>(IDX, U, V, conv_w1, SC0, SH0, BN1S, BN1Q);
    bn_finalize_kernel<<<1, 128, 0, stream>>>(BN1S, BN1Q, bn_g1, bn_b1,
                                              1.0f/262144.0f, 64, SC1, SH1);
    conv2_stats_kernel<<<2048, 256, 0, stream>>>(IDX, U, V, conv_w1, conv_w2,
                                                 SC0, SH0, SC1, SH1, BN2S, BN2Q,
                                                 Y2, useY2);
    bn_finalize_kernel<<<1, 128, 0, stream>>>(BN2S, BN2Q, bn_g2, bn_b2,
                                              1.0f/262144.0f, 128, SC2, SH2);
    if (useY2){
        combine_fast_kernel<<<1024, 256, 0, stream>>>(Y2, ATTW, SC2, SH2, XCOMB, MSUM);
    } else {
        combine_kernel<<<1024, 256, 0, stream>>>(IDX, U, V, conv_w1, conv_w2,
                                                 SC0, SH0, SC1, SH1, SC2, SH2,
                                                 ATTW, XCOMB, MSUM);
    }
    se_kernel<<<1, 128, 0, stream>>>(MSUM, se_w1, se_w2, SEV);
    final_kernel<<<1024, 128, 0, stream>>>(feat, sc_w, XCOMB, SEV, SCSC, SHSC,
                                           (float*)d_out);
}